// Round 5
// baseline (178.814 us; speedup 1.0000x reference)
//
#include <hip/hip_runtime.h>
#include <hip/hip_bf16.h>

// ---------------------------------------------------------------------------
// CDAE forward. Round 15: re-partition phases by dependency depth.
// R14 post-mortem: 178.8->175.7us (predicted 172-175, matched). Fills 124us
// immovable; ours ~52us serial D1->D2->D3. Dependency audit: hidden needs
// only rowsort (5us); bucket (9us) is needed only by D3; yet the 65MB BW
// stream sat in D1 hiding under the SHORTEST latency phase. R15: D1 =
// rowsort || stream-A (512 blk); D2 = hidden || bucket || stream-B; D3 =
// ratings || dot(mask,sq) with last-block finalize of out[N] (atomicAdd +
// threadfence + counter; no dispatch-order assumptions). Same work, two
// fewer serial BW humps.
// Predict k_sort ~6-7, k_mid ~9-11, D3 +0-1; ours 52 -> ~40-44; total
// 175.7 -> ~164-168. If gain <2us => structural floor, declare roofline.
// ---------------------------------------------------------------------------
#define PARTITIONABLE 1
#define NB 8               // item-slice buckets == XCDs (blockIdx&7 pinning)
#define CAPB 136192        // per-item-bucket capacity; E=131072, +14 sigma
#define FATB 2048          // fat grid size for ratings
#define CAPR 128           // per-row capacity; E=40 kept
#define RSB 200            // rowsort blocks: NNZ=204800 = 200 * 4 * 256
#define SA 512             // stream blocks in D1
#define SB 512             // stream blocks in D2
#define TS (SA + SB)       // total stream blocks (grid-stride denominator)
#define HBLK 1024          // hidden blocks (B*64/256)
#define REGF 64            // D3 reg-dot blocks: dot(mask, sq) + finalize
#define REGB_FB 256        // fallback grid size for k_reg_fb

__device__ __forceinline__ unsigned rotl32(unsigned x, int r) {
    return (x << r) | (x >> (32 - r));
}

__device__ __forceinline__ void threefry2x32(unsigned k0, unsigned k1,
                                             unsigned& x0, unsigned& x1) {
    unsigned ks0 = k0, ks1 = k1, ks2 = k0 ^ k1 ^ 0x1BD11BDAu;
    x0 += ks0; x1 += ks1;
#define TF_R(r) { x0 += x1; x1 = rotl32(x1, r); x1 ^= x0; }
    TF_R(13) TF_R(15) TF_R(26) TF_R(6)   x0 += ks1; x1 += ks2 + 1u;
    TF_R(17) TF_R(29) TF_R(16) TF_R(24)  x0 += ks2; x1 += ks0 + 2u;
    TF_R(13) TF_R(15) TF_R(26) TF_R(6)   x0 += ks0; x1 += ks1 + 3u;
    TF_R(17) TF_R(29) TF_R(16) TF_R(24)  x0 += ks1; x1 += ks2 + 4u;
    TF_R(13) TF_R(15) TF_R(26) TF_R(6)   x0 += ks2; x1 += ks0 + 5u;
#undef TF_R
}

__device__ __forceinline__ bool keep_mask(int i, int nnz) {
#if PARTITIONABLE
    unsigned x0 = 0u, x1 = (unsigned)i;
    threefry2x32(0u, 42u, x0, x1);
    unsigned bits = x0 ^ x1;
#else
    int half = nnz >> 1;
    int j = (i < half) ? i : i - half;
    unsigned x0 = (unsigned)j, x1 = (unsigned)(j + half);
    threefry2x32(0u, 42u, x0, x1);
    unsigned bits = (i < half) ? x0 : x1;
#endif
    float u = __uint_as_float((bits >> 9) | 0x3f800000u) - 1.0f;
    return u < 0.8f;
}

// fp32 -> bf16 round-to-nearest-even
__device__ __forceinline__ unsigned short f2bf(float f) {
    unsigned u = __float_as_uint(f);
    return (unsigned short)((u + 0x7FFFu + ((u >> 16) & 1u)) >> 16);
}

// dot of 8 bf16 pairs packed in uint4, fp32 accumulate
__device__ __forceinline__ float bfdot8(uint4 h, uint4 d) {
    float s;
    s  = __uint_as_float(h.x << 16)         * __uint_as_float(d.x << 16);
    s += __uint_as_float(h.x & 0xFFFF0000u) * __uint_as_float(d.x & 0xFFFF0000u);
    s += __uint_as_float(h.y << 16)         * __uint_as_float(d.y << 16);
    s += __uint_as_float(h.y & 0xFFFF0000u) * __uint_as_float(d.y & 0xFFFF0000u);
    s += __uint_as_float(h.z << 16)         * __uint_as_float(d.z << 16);
    s += __uint_as_float(h.z & 0xFFFF0000u) * __uint_as_float(d.z & 0xFFFF0000u);
    s += __uint_as_float(h.w << 16)         * __uint_as_float(d.w << 16);
    s += __uint_as_float(h.w & 0xFFFF0000u) * __uint_as_float(d.w & 0xFFFF0000u);
    return s;
}

// stream body: sq[i] = |en_i|^2+|de_i|^2+bias^2 ; debf = bf16(de_emb)
__device__ __forceinline__ void stream_body(int j, int num_items,
                                            const float* __restrict__ en_emb,
                                            const float* __restrict__ de_emb,
                                            const float* __restrict__ de_bias,
                                            unsigned short* __restrict__ debf,
                                            float* __restrict__ sq) {
    const int stride = TS * 256;
    for (int t = j * 256 + threadIdx.x; t < num_items * 16; t += stride) {
        int i = t >> 4, l = t & 15;
        float4 d = *reinterpret_cast<const float4*>(de_emb + (size_t)i * 64 + l * 4);
        float4 e = *reinterpret_cast<const float4*>(en_emb + (size_t)i * 64 + l * 4);
        ushort4 o;
        o.x = f2bf(d.x); o.y = f2bf(d.y); o.z = f2bf(d.z); o.w = f2bf(d.w);
        reinterpret_cast<ushort4*>(debf)[t] = o;   // t == i*16+l, coalesced
        float q = e.x*e.x + e.y*e.y + e.z*e.z + e.w*e.w
                + d.x*d.x + d.y*d.y + d.z*d.z + d.w*d.w;
        if (l == 0) { float bb = de_bias[i]; q += bb * bb; }
        // 16-lane butterfly: lanes t..t+15 are consecutive, same item i
        q += __shfl_xor(q, 1);
        q += __shfl_xor(q, 2);
        q += __shfl_xor(q, 4);
        q += __shfl_xor(q, 8);
        if (l == 0) sq[i] = q;
    }
}

// ============ D1: rowsort (0..199) || stream-A (200..711) ===================
__global__ void k_sort(const int* __restrict__ sp_row, const int* __restrict__ sp_col,
                       int* __restrict__ rowcur, unsigned* __restrict__ srow,
                       const float* __restrict__ en_emb, const float* __restrict__ de_emb,
                       const float* __restrict__ de_bias,
                       unsigned short* __restrict__ debf, float* __restrict__ sq,
                       int num_items, int nnz, int B) {
    __shared__ int sh[4096];                       // 16KB (rowsort histogram)
    if (blockIdx.x < RSB) {
        // ---- nnz counting-sort by row; compact KEPT entries (bare col) ----
        const int blk = blockIdx.x;
        for (int i = threadIdx.x; i < B; i += blockDim.x) sh[i] = 0;
        __syncthreads();
        const int per = nnz / RSB;                 // 1024
        const int base = blk * per;
        const int iters = per / blockDim.x;        // 4
        unsigned pk[8];
        int rw[8];
        for (int it = 0; it < iters; ++it) {
            int i = base + it * blockDim.x + threadIdx.x;
            int row = sp_row[i];
            int col = sp_col[i];
            bool k = keep_mask(i, nnz);
            pk[it] = (unsigned)col;
            rw[it] = k ? row : -1;
            if (k) atomicAdd(&sh[row], 1);
        }
        __syncthreads();
        for (int i = threadIdx.x; i < B; i += blockDim.x) {
            int c = sh[i];
            if (c) sh[i] = atomicAdd(&rowcur[i], c);
        }
        __syncthreads();
        for (int it = 0; it < iters; ++it) {
            if (rw[it] >= 0) {
                int pos = atomicAdd(&sh[rw[it]], 1);
                srow[(size_t)rw[it] * CAPR + min(pos, CAPR - 1)] = pk[it];
            }
        }
    } else {
        stream_body(blockIdx.x - RSB, num_items, en_emb, de_emb, de_bias, debf, sq);
    }
}

// == D2: hidden (0..1023) || bucket (1024..1279) || stream-B (1280..1791) ====
__global__ void k_mid(const unsigned* __restrict__ srow, const int* __restrict__ rowcur,
                      const float* __restrict__ en_emb, const float* __restrict__ user_emb,
                      const int* __restrict__ user_ids, const float* __restrict__ en_off,
                      unsigned short* __restrict__ hb,
                      const int* __restrict__ bat_idx, const int* __restrict__ bat_items,
                      unsigned char* __restrict__ mask, int* __restrict__ cursor,
                      uint2* __restrict__ perm2,
                      const float* __restrict__ de_emb, const float* __restrict__ de_bias,
                      unsigned short* __restrict__ debf, float* __restrict__ sq,
                      float* __restrict__ reg_ws,
                      int N, int num_items, int B) {
    __shared__ int sh[64];
    if (blockIdx.x < HBLK) {
        // ---- hidden: one wave per row, branch-free 8-chain gather ----
        const int lane = threadIdx.x & 63;
        const int row = (blockIdx.x * blockDim.x + threadIdx.x) >> 6;
        if (row >= B) return;
        const int cnt = min(rowcur[row], CAPR);    // kept entries only
        const unsigned* sr = srow + (size_t)row * CAPR;
        float acc0 = 0.f, acc1 = 0.f, acc2 = 0.f, acc3 = 0.f;
        float acc4 = 0.f, acc5 = 0.f, acc6 = 0.f, acc7 = 0.f;
        for (int j0 = 0; j0 < cnt; j0 += 64) {
            unsigned ev = (j0 + lane < cnt) ? sr[j0 + lane] : 0u;
            int m = min(64, cnt - j0);
            int jj = 0;
            for (; jj + 7 < m; jj += 8) {          // 8 batched, unguarded loads
                unsigned e0 = __shfl(ev, jj);
                unsigned e1 = __shfl(ev, jj + 1);
                unsigned e2 = __shfl(ev, jj + 2);
                unsigned e3 = __shfl(ev, jj + 3);
                unsigned e4 = __shfl(ev, jj + 4);
                unsigned e5 = __shfl(ev, jj + 5);
                unsigned e6 = __shfl(ev, jj + 6);
                unsigned e7 = __shfl(ev, jj + 7);
                acc0 += en_emb[(size_t)e0 * 64 + lane];
                acc1 += en_emb[(size_t)e1 * 64 + lane];
                acc2 += en_emb[(size_t)e2 * 64 + lane];
                acc3 += en_emb[(size_t)e3 * 64 + lane];
                acc4 += en_emb[(size_t)e4 * 64 + lane];
                acc5 += en_emb[(size_t)e5 * 64 + lane];
                acc6 += en_emb[(size_t)e6 * 64 + lane];
                acc7 += en_emb[(size_t)e7 * 64 + lane];
            }
            for (; jj + 3 < m; jj += 4) {
                unsigned e0 = __shfl(ev, jj);
                unsigned e1 = __shfl(ev, jj + 1);
                unsigned e2 = __shfl(ev, jj + 2);
                unsigned e3 = __shfl(ev, jj + 3);
                acc0 += en_emb[(size_t)e0 * 64 + lane];
                acc1 += en_emb[(size_t)e1 * 64 + lane];
                acc2 += en_emb[(size_t)e2 * 64 + lane];
                acc3 += en_emb[(size_t)e3 * 64 + lane];
            }
            for (; jj < m; ++jj) {
                unsigned e0 = __shfl(ev, jj);
                acc0 += en_emb[(size_t)e0 * 64 + lane];
            }
        }
        int uid = user_ids[row];
        float hval = 1.25f * (((acc0 + acc1) + (acc2 + acc3))
                            + ((acc4 + acc5) + (acc6 + acc7)))
                   + user_emb[(size_t)uid * 64 + lane] + en_off[lane];
        hb[(size_t)row * 64 + lane] = f2bf(tanhf(hval));
    } else if (blockIdx.x < HBLK + 256) {
        // ---- pair bucketing by item slice; payload carries n ----
        const int bb = blockIdx.x - HBLK;
        if (threadIdx.x < NB) sh[threadIdx.x] = 0;
        __syncthreads();
        const int per = N / 256;                   // 4096
        const int base_n = bb * per;
        const int iters = per / blockDim.x;        // 16
        unsigned packed[16];
        int bkt[16];
        for (int it = 0; it < iters; ++it) {
            int n = base_n + it * blockDim.x + threadIdx.x;
            int item = bat_items[n];
            int bidx = bat_idx[n];
            mask[item] = 1;
            int b = (int)(((unsigned long long)(unsigned)item * NB) / (unsigned)num_items);
            packed[it] = ((unsigned)item << 12) | (unsigned)bidx;   // item:17|bidx:12
            bkt[it] = b;
            atomicAdd(&sh[b], 1);
        }
        __syncthreads();
        if (threadIdx.x < NB) {
            int c = sh[threadIdx.x];
            sh[threadIdx.x] = atomicAdd(&cursor[threadIdx.x], c);
        }
        __syncthreads();
        for (int it = 0; it < iters; ++it) {
            int n = base_n + it * blockDim.x + threadIdx.x;
            int pos = atomicAdd(&sh[bkt[it]], 1);
            unsigned gpos = (unsigned)bkt[it] * CAPB + (unsigned)min(pos, CAPB - 1);
            perm2[gpos] = make_uint2(packed[it], (unsigned)n);  // run-contiguous
        }
    } else {
        // ---- stream-B + user/offset reg terms ----
        const int j2 = blockIdx.x - (HBLK + 256);  // [0, SB)
        stream_body(SA + j2, num_items, en_emb, de_emb, de_bias, debf, sq);
        float s = 0.f;
        const int stride2 = SB * 256;
        for (int t = j2 * 256 + threadIdx.x; t < B * 16; t += stride2) {
            int b = t >> 4, l = t & 15;
            int uid = user_ids[b];
            float4 u = *reinterpret_cast<const float4*>(user_emb + (size_t)uid * 64 + l * 4);
            s += u.x*u.x + u.y*u.y + u.z*u.z + u.w*u.w;
        }
        if (j2 == 0 && threadIdx.x < 64) {
            float o = en_off[threadIdx.x];
            s += o * o;
        }
        for (int m = 1; m < 64; m <<= 1) s += __shfl_xor(s, m);
        float* wsum = (float*)sh;
        if ((threadIdx.x & 63) == 0) wsum[threadIdx.x >> 6] = s;
        __syncthreads();
        if (threadIdx.x == 0)
            atomicAdd(reg_ws, wsum[0] + wsum[1] + wsum[2] + wsum[3]);
    }
}

// D3: reg-dot+finalize (0..63) || ratings 8-lane groups, direct scatter ======
__global__ void k_ratings_bkt(const unsigned short* __restrict__ hb,
                              const unsigned short* __restrict__ debf,
                              const float* __restrict__ de_bias,
                              const uint2* __restrict__ perm2, const int* __restrict__ cursor,
                              const unsigned char* __restrict__ mask,
                              const float* __restrict__ sq,
                              float* __restrict__ reg_ws, int* __restrict__ done_cnt,
                              float* __restrict__ out, int N, int num_items) {
    if (blockIdx.x < REGF) {
        // ---- reg finish: sum_i mask[i]*sq[i]; last block writes out[N] ----
        const int stride = REGF * blockDim.x;
        float s = 0.f;
        for (int i = blockIdx.x * blockDim.x + threadIdx.x; i < num_items; i += stride)
            s += (float)mask[i] * sq[i];
        for (int m = 1; m < 64; m <<= 1) s += __shfl_xor(s, m);
        __shared__ float wsum[4];
        if ((threadIdx.x & 63) == 0) wsum[threadIdx.x >> 6] = s;
        __syncthreads();
        if (threadIdx.x == 0) {
            atomicAdd(reg_ws, wsum[0] + wsum[1] + wsum[2] + wsum[3]);
            __threadfence();
            int old = atomicAdd(done_cnt, 1);
            if (old == REGF - 1)
                out[N] = 0.5f * atomicAdd(reg_ws, 0.0f);   // coherent read
        }
        return;
    }
    const int bid = blockIdx.x - REGF;
    const int bkt = bid & (NB - 1);
    const int cnt = cursor[bkt];
    const int l = threadIdx.x & 7;                        // 8 lanes per pair
    const int gid = (bid >> 3) * (blockDim.x >> 3) + (threadIdx.x >> 3);
    const int gpb = ((gridDim.x - REGF) >> 3) * (blockDim.x >> 3); // groups/bucket
    const uint2* pb = perm2 + (size_t)bkt * CAPB;

    int slot = gid;
    for (; slot + 3 * gpb < cnt; slot += 4 * gpb) {       // 4 independent chains
        uint2 p0 = pb[slot];
        uint2 p1 = pb[slot + gpb];
        uint2 p2 = pb[slot + 2 * gpb];
        uint2 p3 = pb[slot + 3 * gpb];
        int it0 = (int)(p0.x >> 12), b0 = (int)(p0.x & 0xFFFu);
        int it1 = (int)(p1.x >> 12), b1 = (int)(p1.x & 0xFFFu);
        int it2 = (int)(p2.x >> 12), b2 = (int)(p2.x & 0xFFFu);
        int it3 = (int)(p3.x >> 12), b3 = (int)(p3.x & 0xFFFu);
        uint4 h0 = *reinterpret_cast<const uint4*>(hb   + (size_t)b0  * 64 + l * 8);
        uint4 d0 = *reinterpret_cast<const uint4*>(debf + (size_t)it0 * 64 + l * 8);
        uint4 h1 = *reinterpret_cast<const uint4*>(hb   + (size_t)b1  * 64 + l * 8);
        uint4 d1 = *reinterpret_cast<const uint4*>(debf + (size_t)it1 * 64 + l * 8);
        uint4 h2 = *reinterpret_cast<const uint4*>(hb   + (size_t)b2  * 64 + l * 8);
        uint4 d2 = *reinterpret_cast<const uint4*>(debf + (size_t)it2 * 64 + l * 8);
        uint4 h3 = *reinterpret_cast<const uint4*>(hb   + (size_t)b3  * 64 + l * 8);
        uint4 d3 = *reinterpret_cast<const uint4*>(debf + (size_t)it3 * 64 + l * 8);
        float s0 = bfdot8(h0, d0);
        float s1 = bfdot8(h1, d1);
        float s2 = bfdot8(h2, d2);
        float s3 = bfdot8(h3, d3);
        s0 += __shfl_xor(s0, 1); s1 += __shfl_xor(s1, 1);
        s2 += __shfl_xor(s2, 1); s3 += __shfl_xor(s3, 1);
        s0 += __shfl_xor(s0, 2); s1 += __shfl_xor(s1, 2);
        s2 += __shfl_xor(s2, 2); s3 += __shfl_xor(s3, 2);
        s0 += __shfl_xor(s0, 4); s1 += __shfl_xor(s1, 4);
        s2 += __shfl_xor(s2, 4); s3 += __shfl_xor(s3, 4);
        if (l == 0) {
            out[p0.y] = s0 + de_bias[it0];
            out[p1.y] = s1 + de_bias[it1];
            out[p2.y] = s2 + de_bias[it2];
            out[p3.y] = s3 + de_bias[it3];
        }
    }
    for (; slot < cnt; slot += gpb) {
        uint2 p = pb[slot];
        int item = (int)(p.x >> 12), bidx = (int)(p.x & 0xFFFu);
        uint4 hv = *reinterpret_cast<const uint4*>(hb   + (size_t)bidx * 64 + l * 8);
        uint4 dv = *reinterpret_cast<const uint4*>(debf + (size_t)item * 64 + l * 8);
        float s = bfdot8(hv, dv);
        s += __shfl_xor(s, 1);
        s += __shfl_xor(s, 2);
        s += __shfl_xor(s, 4);
        if (l == 0) out[p.y] = s + de_bias[item];
    }
}

// ===================== fallback (direct) path ===============================
__global__ void k_mask(const int* __restrict__ bat_items, unsigned char* __restrict__ mask,
                       int N) {
    int t = blockIdx.x * blockDim.x + threadIdx.x;
    if (t < N) mask[bat_items[t]] = 1;
}

__global__ void k_ratings(const float* __restrict__ hidden, const float* __restrict__ de_emb,
                          const float* __restrict__ de_bias,
                          const int* __restrict__ bat_idx, const int* __restrict__ bat_items,
                          float* __restrict__ out, int N) {
    const int l = threadIdx.x & 15;
    const int gid = (blockIdx.x * blockDim.x + threadIdx.x) >> 4;
    const int gstride = (gridDim.x * blockDim.x) >> 4;
    for (int n = gid; n < N; n += gstride) {
        int b  = bat_idx[n];
        int it = bat_items[n];
        float4 hv = *reinterpret_cast<const float4*>(hidden + (size_t)b  * 64 + l * 4);
        float4 dv = *reinterpret_cast<const float4*>(de_emb + (size_t)it * 64 + l * 4);
        float s = hv.x*dv.x + hv.y*dv.y + hv.z*dv.z + hv.w*dv.w;
        s += __shfl_xor(s, 1);
        s += __shfl_xor(s, 2);
        s += __shfl_xor(s, 4);
        s += __shfl_xor(s, 8);
        if (l == 0) out[n] = s + de_bias[it];
    }
}

__global__ void k_scatter(const int* __restrict__ sp_row, const int* __restrict__ sp_col,
                          const float* __restrict__ en_emb, float* __restrict__ hidden,
                          int nnz) {
    const int lane = threadIdx.x & 63;
    const int wave = (blockIdx.x * blockDim.x + threadIdx.x) >> 6;
    const int nwaves = (gridDim.x * blockDim.x) >> 6;
    for (int i = wave; i < nnz; i += nwaves) {
        if (!keep_mask(i, nnz)) continue;
        int row = sp_row[i];
        int col = sp_col[i];
        float v = 1.25f * en_emb[(size_t)col * 64 + lane];
        atomicAdd(&hidden[row * 64 + lane], v);
    }
}

__global__ void k_hfinish(float* __restrict__ hidden, const float* __restrict__ user_emb,
                          const int* __restrict__ user_ids, const float* __restrict__ en_off,
                          int B) {
    int t = blockIdx.x * blockDim.x + threadIdx.x;
    if (t >= B * 64) return;
    int b = t >> 6, d = t & 63;
    int uid = user_ids[b];
    float h = hidden[t] + user_emb[(size_t)uid * 64 + d] + en_off[d];
    hidden[t] = tanhf(h);
}

__global__ void k_reg_fb(const unsigned char* __restrict__ mask,
                         const float* __restrict__ en_emb, const float* __restrict__ de_emb,
                         const float* __restrict__ de_bias,
                         const float* __restrict__ user_emb, const int* __restrict__ user_ids,
                         const float* __restrict__ en_off,
                         float* __restrict__ reg, int num_items, int B) {
    const int stride = gridDim.x * blockDim.x;
    float s = 0.f;
    for (int t = blockIdx.x * blockDim.x + threadIdx.x; t < num_items * 16; t += stride) {
        int i = t >> 4, l = t & 15;
        if (mask[i]) {
            float4 e = *reinterpret_cast<const float4*>(en_emb + (size_t)i * 64 + l * 4);
            float4 d = *reinterpret_cast<const float4*>(de_emb + (size_t)i * 64 + l * 4);
            s += e.x*e.x + e.y*e.y + e.z*e.z + e.w*e.w
               + d.x*d.x + d.y*d.y + d.z*d.z + d.w*d.w;
            if (l == 0) { float bb = de_bias[i]; s += bb * bb; }
        }
    }
    for (int t = blockIdx.x * blockDim.x + threadIdx.x; t < B * 16; t += stride) {
        int b = t >> 4, l = t & 15;
        int uid = user_ids[b];
        float4 u = *reinterpret_cast<const float4*>(user_emb + (size_t)uid * 64 + l * 4);
        s += u.x*u.x + u.y*u.y + u.z*u.z + u.w*u.w;
    }
    if (blockIdx.x == 0 && threadIdx.x < 64) {
        float o = en_off[threadIdx.x];
        s += o * o;
    }
    for (int m = 1; m < 64; m <<= 1) s += __shfl_xor(s, m);
    __shared__ float wsum[4];
    if ((threadIdx.x & 63) == 0) wsum[threadIdx.x >> 6] = s;
    __syncthreads();
    if (threadIdx.x == 0)
        atomicAdd(reg, 0.5f * (wsum[0] + wsum[1] + wsum[2] + wsum[3]));
}

extern "C" void kernel_launch(void* const* d_in, const int* in_sizes, int n_in,
                              void* d_out, int out_size, void* d_ws, size_t ws_size,
                              hipStream_t stream) {
    const int*   user_ids  = (const int*)  d_in[0];
    const int*   bat_idx   = (const int*)  d_in[1];
    const int*   sp_row    = (const int*)  d_in[2];
    const int*   sp_col    = (const int*)  d_in[3];
    const int*   bat_items = (const int*)  d_in[4];
    const float* en_emb    = (const float*)d_in[5];
    const float* en_off    = (const float*)d_in[6];
    const float* de_emb    = (const float*)d_in[7];
    const float* de_bias   = (const float*)d_in[8];
    const float* user_emb  = (const float*)d_in[9];

    const int B         = in_sizes[0];
    const int N         = in_sizes[1];
    const int NNZ       = in_sizes[2];
    const int NUM_ITEMS = in_sizes[8];

    float* out = (float*)d_out;        // ratings [N]; reg scalar at out[N]

    // workspace: [mask | cursor | rowcur | reg_ws+done] one memset; rest raw.
    char* ws = (char*)d_ws;
    size_t off = 0;
    unsigned char* mask = (unsigned char*)(ws + off);
    off += ((size_t)NUM_ITEMS + 255) & ~(size_t)255;
    int* cursor = (int*)(ws + off);               off += 256;
    int* rowcur = (int*)(ws + off);               off += (size_t)B * 4;
    float* reg_ws = (float*)(ws + off);
    int* done_cnt = (int*)(ws + off) + 1;         off += 256;
    const size_t zero_bytes = off;
    float* hidden = (float*)(ws + off);           off += (size_t)B * 64 * 4;  // fallback only
    off = (off + 15) & ~(size_t)15;
    uint2* perm2 = (uint2*)(ws + off);            off += (size_t)NB * CAPB * 8;
    unsigned* srow = (unsigned*)(ws + off);       off += (size_t)B * CAPR * 4;
    unsigned short* hb   = (unsigned short*)(ws + off);  off += (size_t)B * 64 * 2;
    off = (off + 15) & ~(size_t)15;
    unsigned short* debf = (unsigned short*)(ws + off);  off += (size_t)NUM_ITEMS * 64 * 2;
    float* sq = (float*)(ws + off);                      off += (size_t)NUM_ITEMS * 4;

    const bool sorted_path =
        (ws_size >= off) && (N == (1 << 20)) && (B == 4096) &&
        (NUM_ITEMS <= (1 << 17)) && (NUM_ITEMS >= 65536) &&
        (NUM_ITEMS % 4 == 0) &&
        (NNZ % (RSB * 256) == 0) && (NNZ / RSB <= CAPR * 256);

    hipMemsetAsync(ws, 0, zero_bytes, stream);

    if (sorted_path) {
        k_sort<<<RSB + SA, 256, 0, stream>>>(
            sp_row, sp_col, rowcur, srow,
            en_emb, de_emb, de_bias, debf, sq, NUM_ITEMS, NNZ, B);
        k_mid<<<HBLK + 256 + SB, 256, 0, stream>>>(
            srow, rowcur, en_emb, user_emb, user_ids, en_off, hb,
            bat_idx, bat_items, mask, cursor, perm2,
            de_emb, de_bias, debf, sq, reg_ws, N, NUM_ITEMS, B);
        k_ratings_bkt<<<REGF + FATB, 256, 0, stream>>>(
            hb, debf, de_bias, perm2, cursor, mask, sq,
            reg_ws, done_cnt, out, N, NUM_ITEMS);
    } else {
        hipMemsetAsync(hidden, 0, (size_t)B * 64 * 4, stream);
        hipMemsetAsync(out + N, 0, sizeof(float), stream);
        k_mask<<<(N + 255) / 256, 256, 0, stream>>>(bat_items, mask, N);
        k_scatter<<<FATB, 256, 0, stream>>>(sp_row, sp_col, en_emb, hidden, NNZ);
        k_hfinish<<<(B * 64 + 255) / 256, 256, 0, stream>>>(hidden, user_emb, user_ids,
                                                            en_off, B);
        k_ratings<<<FATB, 256, 0, stream>>>(hidden, de_emb, de_bias, bat_idx, bat_items, out, N);
        k_reg_fb<<<REGB_FB, 256, 0, stream>>>(mask, en_emb, de_emb, de_bias,
                                              user_emb, user_ids, en_off, out + N, NUM_ITEMS, B);
    }
}

// Round 6
// 175.292 us; speedup vs baseline: 1.0201x; 1.0201x over previous
//
#include <hip/hip_runtime.h>
#include <hip/hip_bf16.h>

// ---------------------------------------------------------------------------
// CDAE forward. Round 16: REVERT to R14 (best measured, 175.7us).
// R15 post-mortem: 175.7->178.8 (hurt; theory wrong). Re-partition assumed
// phase walls compose as max() of co-resident branches -- false when the
// long pole is LATENCY-bound: hidden (1-wave/row gather) lost CU share to
// co-scheduled bucket+stream blocks in D2; sum-like, not max-like. R14's
// assignment was already optimal: BW stream hides under atomic/latency-light
// bucket+rowsort (idle issue slots), hidden runs alone in D2.
// Structure: D1 = bucket || rowsort || sq/cvt stream; D2 = hidden || reg-dot;
// D3 = ratings + direct scatter via perm2{packed,n} + out[N] finalize.
// Predict: ~175-176us, top-5 all poison fills @82-85% HBM (immovable).
// Remaining budget: ~124us fills + ~40us ours (near gather/BW floor) +
// launch gaps. If this reproduces ~175-176 => declare ROOFLINE next round.
// ---------------------------------------------------------------------------
#define PARTITIONABLE 1
#define NB 8               // item-slice buckets == XCDs (blockIdx&7 pinning)
#define CAPB 136192        // per-item-bucket capacity; E=131072, +14 sigma
#define FATB 2048          // fat grid size for ratings
#define CAPR 128           // per-row capacity; E=40 kept
#define RSB 200            // rowsort blocks: NNZ=204800 = 200 * 4 * 256
#define SCVT 1024          // D1 streaming branch blocks (en/de sq + cvt)
#define HBLK 1024          // hidden blocks (B*64/256)
#define REGF 64            // D2 reg-finish blocks: dot(mask, sq)
#define REGB_FB 256        // fallback grid size for k_reg_fb

__device__ __forceinline__ unsigned rotl32(unsigned x, int r) {
    return (x << r) | (x >> (32 - r));
}

__device__ __forceinline__ void threefry2x32(unsigned k0, unsigned k1,
                                             unsigned& x0, unsigned& x1) {
    unsigned ks0 = k0, ks1 = k1, ks2 = k0 ^ k1 ^ 0x1BD11BDAu;
    x0 += ks0; x1 += ks1;
#define TF_R(r) { x0 += x1; x1 = rotl32(x1, r); x1 ^= x0; }
    TF_R(13) TF_R(15) TF_R(26) TF_R(6)   x0 += ks1; x1 += ks2 + 1u;
    TF_R(17) TF_R(29) TF_R(16) TF_R(24)  x0 += ks2; x1 += ks0 + 2u;
    TF_R(13) TF_R(15) TF_R(26) TF_R(6)   x0 += ks0; x1 += ks1 + 3u;
    TF_R(17) TF_R(29) TF_R(16) TF_R(24)  x0 += ks1; x1 += ks2 + 4u;
    TF_R(13) TF_R(15) TF_R(26) TF_R(6)   x0 += ks2; x1 += ks0 + 5u;
#undef TF_R
}

__device__ __forceinline__ bool keep_mask(int i, int nnz) {
#if PARTITIONABLE
    unsigned x0 = 0u, x1 = (unsigned)i;
    threefry2x32(0u, 42u, x0, x1);
    unsigned bits = x0 ^ x1;
#else
    int half = nnz >> 1;
    int j = (i < half) ? i : i - half;
    unsigned x0 = (unsigned)j, x1 = (unsigned)(j + half);
    threefry2x32(0u, 42u, x0, x1);
    unsigned bits = (i < half) ? x0 : x1;
#endif
    float u = __uint_as_float((bits >> 9) | 0x3f800000u) - 1.0f;
    return u < 0.8f;
}

// fp32 -> bf16 round-to-nearest-even
__device__ __forceinline__ unsigned short f2bf(float f) {
    unsigned u = __float_as_uint(f);
    return (unsigned short)((u + 0x7FFFu + ((u >> 16) & 1u)) >> 16);
}

// dot of 8 bf16 pairs packed in uint4, fp32 accumulate
__device__ __forceinline__ float bfdot8(uint4 h, uint4 d) {
    float s;
    s  = __uint_as_float(h.x << 16)         * __uint_as_float(d.x << 16);
    s += __uint_as_float(h.x & 0xFFFF0000u) * __uint_as_float(d.x & 0xFFFF0000u);
    s += __uint_as_float(h.y << 16)         * __uint_as_float(d.y << 16);
    s += __uint_as_float(h.y & 0xFFFF0000u) * __uint_as_float(d.y & 0xFFFF0000u);
    s += __uint_as_float(h.z << 16)         * __uint_as_float(d.z << 16);
    s += __uint_as_float(h.z & 0xFFFF0000u) * __uint_as_float(d.z & 0xFFFF0000u);
    s += __uint_as_float(h.w << 16)         * __uint_as_float(d.w << 16);
    s += __uint_as_float(h.w & 0xFFFF0000u) * __uint_as_float(d.w & 0xFFFF0000u);
    return s;
}

// == D1: bucket (0..255) || rowsort (256..455) || sq/cvt stream (456..) =====
__global__ void k_prep(const int* __restrict__ bat_idx, const int* __restrict__ bat_items,
                       unsigned char* __restrict__ mask, int* __restrict__ cursor,
                       uint2* __restrict__ perm2,
                       const int* __restrict__ sp_row, const int* __restrict__ sp_col,
                       int* __restrict__ rowcur, unsigned* __restrict__ srow,
                       const float* __restrict__ en_emb, const float* __restrict__ de_emb,
                       const float* __restrict__ de_bias, const float* __restrict__ user_emb,
                       const int* __restrict__ user_ids, const float* __restrict__ en_off,
                       unsigned short* __restrict__ debf, float* __restrict__ sq,
                       float* __restrict__ reg_ws,
                       int N, int num_items, int nnz, int B) {
    __shared__ int sh[4096];                       // 16KB, shared by all branches
    if (blockIdx.x < 256) {
        // ---- pair bucketing by item slice; payload carries n ----
        if (threadIdx.x < NB) sh[threadIdx.x] = 0;
        __syncthreads();
        const int per = N / 256;                   // 4096
        const int base_n = blockIdx.x * per;
        const int iters = per / blockDim.x;        // 16
        unsigned packed[16];
        int bkt[16];
        for (int it = 0; it < iters; ++it) {
            int n = base_n + it * blockDim.x + threadIdx.x;
            int item = bat_items[n];
            int bidx = bat_idx[n];
            mask[item] = 1;
            int b = (int)(((unsigned long long)(unsigned)item * NB) / (unsigned)num_items);
            packed[it] = ((unsigned)item << 12) | (unsigned)bidx;   // item:17|bidx:12
            bkt[it] = b;
            atomicAdd(&sh[b], 1);
        }
        __syncthreads();
        if (threadIdx.x < NB) {
            int c = sh[threadIdx.x];
            sh[threadIdx.x] = atomicAdd(&cursor[threadIdx.x], c);
        }
        __syncthreads();
        for (int it = 0; it < iters; ++it) {
            int n = base_n + it * blockDim.x + threadIdx.x;
            int pos = atomicAdd(&sh[bkt[it]], 1);
            unsigned gpos = (unsigned)bkt[it] * CAPB + (unsigned)min(pos, CAPB - 1);
            perm2[gpos] = make_uint2(packed[it], (unsigned)n);  // run-contiguous
        }
    } else if (blockIdx.x < 256 + RSB) {
        // ---- nnz counting-sort by row; compact KEPT entries (bare col) ----
        const int blk = blockIdx.x - 256;
        for (int i = threadIdx.x; i < B; i += blockDim.x) sh[i] = 0;
        __syncthreads();
        const int per = nnz / RSB;                 // 1024
        const int base = blk * per;
        const int iters = per / blockDim.x;        // 4
        unsigned pk[8];
        int rw[8];
        for (int it = 0; it < iters; ++it) {
            int i = base + it * blockDim.x + threadIdx.x;
            int row = sp_row[i];
            int col = sp_col[i];
            bool k = keep_mask(i, nnz);
            pk[it] = (unsigned)col;
            rw[it] = k ? row : -1;
            if (k) atomicAdd(&sh[row], 1);
        }
        __syncthreads();
        for (int i = threadIdx.x; i < B; i += blockDim.x) {
            int c = sh[i];
            if (c) sh[i] = atomicAdd(&rowcur[i], c);
        }
        __syncthreads();
        for (int it = 0; it < iters; ++it) {
            if (rw[it] >= 0) {
                int pos = atomicAdd(&sh[rw[it]], 1);
                srow[(size_t)rw[it] * CAPR + min(pos, CAPR - 1)] = pk[it];
            }
        }
    } else {
        // ---- mask-free reg terms + de_emb->bf16 cvt (the 65MB stream) ----
        // sq[i] = |en_i|^2 + |de_i|^2 + bias_i^2 ; D2 finishes with mask dot.
        const int bx = blockIdx.x - (256 + RSB);
        const int stride = SCVT * blockDim.x;
        for (int t = bx * blockDim.x + threadIdx.x; t < num_items * 16; t += stride) {
            int i = t >> 4, l = t & 15;
            float4 d = *reinterpret_cast<const float4*>(de_emb + (size_t)i * 64 + l * 4);
            float4 e = *reinterpret_cast<const float4*>(en_emb + (size_t)i * 64 + l * 4);
            ushort4 o;
            o.x = f2bf(d.x); o.y = f2bf(d.y); o.z = f2bf(d.z); o.w = f2bf(d.w);
            reinterpret_cast<ushort4*>(debf)[t] = o;   // t == i*16+l, coalesced
            float q = e.x*e.x + e.y*e.y + e.z*e.z + e.w*e.w
                    + d.x*d.x + d.y*d.y + d.z*d.z + d.w*d.w;
            if (l == 0) { float bb = de_bias[i]; q += bb * bb; }
            // 16-lane butterfly: lanes t..t+15 are consecutive, same item i
            q += __shfl_xor(q, 1);
            q += __shfl_xor(q, 2);
            q += __shfl_xor(q, 4);
            q += __shfl_xor(q, 8);
            if (l == 0) sq[i] = q;
        }
        float s = 0.f;
        for (int t = bx * blockDim.x + threadIdx.x; t < B * 16; t += stride) {
            int b = t >> 4, l = t & 15;
            int uid = user_ids[b];
            float4 u = *reinterpret_cast<const float4*>(user_emb + (size_t)uid * 64 + l * 4);
            s += u.x*u.x + u.y*u.y + u.z*u.z + u.w*u.w;
        }
        if (bx == 0 && threadIdx.x < 64) {
            float o = en_off[threadIdx.x];
            s += o * o;
        }
        for (int m = 1; m < 64; m <<= 1) s += __shfl_xor(s, m);
        float* wsum = (float*)sh;
        if ((threadIdx.x & 63) == 0) wsum[threadIdx.x >> 6] = s;
        __syncthreads();
        if (threadIdx.x == 0)
            atomicAdd(reg_ws, wsum[0] + wsum[1] + wsum[2] + wsum[3]);
    }
}

// ==== D2: hidden (0..1023) || reg finish: dot(mask, sq) (1024..1087) ========
__global__ void k_hidden_reg(const unsigned* __restrict__ srow, const int* __restrict__ rowcur,
                             const float* __restrict__ en_emb, const float* __restrict__ user_emb,
                             const int* __restrict__ user_ids, const float* __restrict__ en_off,
                             unsigned short* __restrict__ hb,
                             const unsigned char* __restrict__ mask,
                             const float* __restrict__ sq,
                             float* __restrict__ reg_ws, int B, int num_items) {
    if (blockIdx.x < HBLK) {
        // ---- hidden: one wave per row, branch-free 8-chain gather ----
        const int lane = threadIdx.x & 63;
        const int row = (blockIdx.x * blockDim.x + threadIdx.x) >> 6;
        if (row >= B) return;
        const int cnt = min(rowcur[row], CAPR);    // kept entries only
        const unsigned* sr = srow + (size_t)row * CAPR;
        float acc0 = 0.f, acc1 = 0.f, acc2 = 0.f, acc3 = 0.f;
        float acc4 = 0.f, acc5 = 0.f, acc6 = 0.f, acc7 = 0.f;
        for (int j0 = 0; j0 < cnt; j0 += 64) {
            unsigned ev = (j0 + lane < cnt) ? sr[j0 + lane] : 0u;
            int m = min(64, cnt - j0);
            int jj = 0;
            for (; jj + 7 < m; jj += 8) {          // 8 batched, unguarded loads
                unsigned e0 = __shfl(ev, jj);
                unsigned e1 = __shfl(ev, jj + 1);
                unsigned e2 = __shfl(ev, jj + 2);
                unsigned e3 = __shfl(ev, jj + 3);
                unsigned e4 = __shfl(ev, jj + 4);
                unsigned e5 = __shfl(ev, jj + 5);
                unsigned e6 = __shfl(ev, jj + 6);
                unsigned e7 = __shfl(ev, jj + 7);
                acc0 += en_emb[(size_t)e0 * 64 + lane];
                acc1 += en_emb[(size_t)e1 * 64 + lane];
                acc2 += en_emb[(size_t)e2 * 64 + lane];
                acc3 += en_emb[(size_t)e3 * 64 + lane];
                acc4 += en_emb[(size_t)e4 * 64 + lane];
                acc5 += en_emb[(size_t)e5 * 64 + lane];
                acc6 += en_emb[(size_t)e6 * 64 + lane];
                acc7 += en_emb[(size_t)e7 * 64 + lane];
            }
            for (; jj + 3 < m; jj += 4) {
                unsigned e0 = __shfl(ev, jj);
                unsigned e1 = __shfl(ev, jj + 1);
                unsigned e2 = __shfl(ev, jj + 2);
                unsigned e3 = __shfl(ev, jj + 3);
                acc0 += en_emb[(size_t)e0 * 64 + lane];
                acc1 += en_emb[(size_t)e1 * 64 + lane];
                acc2 += en_emb[(size_t)e2 * 64 + lane];
                acc3 += en_emb[(size_t)e3 * 64 + lane];
            }
            for (; jj < m; ++jj) {
                unsigned e0 = __shfl(ev, jj);
                acc0 += en_emb[(size_t)e0 * 64 + lane];
            }
        }
        int uid = user_ids[row];
        float hval = 1.25f * (((acc0 + acc1) + (acc2 + acc3))
                            + ((acc4 + acc5) + (acc6 + acc7)))
                   + user_emb[(size_t)uid * 64 + lane] + en_off[lane];
        hb[(size_t)row * 64 + lane] = f2bf(tanhf(hval));
    } else {
        // ---- reg finish: s = sum_i mask[i] * sq[i]  (0.5MB, trivial) ----
        const int bx = blockIdx.x - HBLK;
        const int stride = REGF * blockDim.x;
        float s = 0.f;
        for (int i = bx * blockDim.x + threadIdx.x; i < num_items; i += stride)
            s += (float)mask[i] * sq[i];
        for (int m = 1; m < 64; m <<= 1) s += __shfl_xor(s, m);
        __shared__ float wsum[4];
        if ((threadIdx.x & 63) == 0) wsum[threadIdx.x >> 6] = s;
        __syncthreads();
        if (threadIdx.x == 0)
            atomicAdd(reg_ws, wsum[0] + wsum[1] + wsum[2] + wsum[3]);
    }
}

// == D3: ratings, 8-lane groups, uint4 bf16 loads, 4 chains, direct scatter ==
__global__ void k_ratings_bkt(const unsigned short* __restrict__ hb,
                              const unsigned short* __restrict__ debf,
                              const float* __restrict__ de_bias,
                              const uint2* __restrict__ perm2, const int* __restrict__ cursor,
                              const float* __restrict__ reg_ws,
                              float* __restrict__ out, int N) {
    if (blockIdx.x == 0 && threadIdx.x == 0)
        out[N] = 0.5f * reg_ws[0];                        // reg_ws final after D2
    const int bkt = blockIdx.x & (NB - 1);
    const int cnt = cursor[bkt];
    const int l = threadIdx.x & 7;                        // 8 lanes per pair
    const int gid = (blockIdx.x >> 3) * (blockDim.x >> 3) + (threadIdx.x >> 3);
    const int gpb = (gridDim.x >> 3) * (blockDim.x >> 3); // groups per bucket
    const uint2* pb = perm2 + (size_t)bkt * CAPB;

    int slot = gid;
    for (; slot + 3 * gpb < cnt; slot += 4 * gpb) {       // 4 independent chains
        uint2 p0 = pb[slot];
        uint2 p1 = pb[slot + gpb];
        uint2 p2 = pb[slot + 2 * gpb];
        uint2 p3 = pb[slot + 3 * gpb];
        int it0 = (int)(p0.x >> 12), b0 = (int)(p0.x & 0xFFFu);
        int it1 = (int)(p1.x >> 12), b1 = (int)(p1.x & 0xFFFu);
        int it2 = (int)(p2.x >> 12), b2 = (int)(p2.x & 0xFFFu);
        int it3 = (int)(p3.x >> 12), b3 = (int)(p3.x & 0xFFFu);
        uint4 h0 = *reinterpret_cast<const uint4*>(hb   + (size_t)b0  * 64 + l * 8);
        uint4 d0 = *reinterpret_cast<const uint4*>(debf + (size_t)it0 * 64 + l * 8);
        uint4 h1 = *reinterpret_cast<const uint4*>(hb   + (size_t)b1  * 64 + l * 8);
        uint4 d1 = *reinterpret_cast<const uint4*>(debf + (size_t)it1 * 64 + l * 8);
        uint4 h2 = *reinterpret_cast<const uint4*>(hb   + (size_t)b2  * 64 + l * 8);
        uint4 d2 = *reinterpret_cast<const uint4*>(debf + (size_t)it2 * 64 + l * 8);
        uint4 h3 = *reinterpret_cast<const uint4*>(hb   + (size_t)b3  * 64 + l * 8);
        uint4 d3 = *reinterpret_cast<const uint4*>(debf + (size_t)it3 * 64 + l * 8);
        float s0 = bfdot8(h0, d0);
        float s1 = bfdot8(h1, d1);
        float s2 = bfdot8(h2, d2);
        float s3 = bfdot8(h3, d3);
        s0 += __shfl_xor(s0, 1); s1 += __shfl_xor(s1, 1);
        s2 += __shfl_xor(s2, 1); s3 += __shfl_xor(s3, 1);
        s0 += __shfl_xor(s0, 2); s1 += __shfl_xor(s1, 2);
        s2 += __shfl_xor(s2, 2); s3 += __shfl_xor(s3, 2);
        s0 += __shfl_xor(s0, 4); s1 += __shfl_xor(s1, 4);
        s2 += __shfl_xor(s2, 4); s3 += __shfl_xor(s3, 4);
        if (l == 0) {
            out[p0.y] = s0 + de_bias[it0];
            out[p1.y] = s1 + de_bias[it1];
            out[p2.y] = s2 + de_bias[it2];
            out[p3.y] = s3 + de_bias[it3];
        }
    }
    for (; slot < cnt; slot += gpb) {
        uint2 p = pb[slot];
        int item = (int)(p.x >> 12), bidx = (int)(p.x & 0xFFFu);
        uint4 hv = *reinterpret_cast<const uint4*>(hb   + (size_t)bidx * 64 + l * 8);
        uint4 dv = *reinterpret_cast<const uint4*>(debf + (size_t)item * 64 + l * 8);
        float s = bfdot8(hv, dv);
        s += __shfl_xor(s, 1);
        s += __shfl_xor(s, 2);
        s += __shfl_xor(s, 4);
        if (l == 0) out[p.y] = s + de_bias[item];
    }
}

// ===================== fallback (direct) path ===============================
__global__ void k_mask(const int* __restrict__ bat_items, unsigned char* __restrict__ mask,
                       int N) {
    int t = blockIdx.x * blockDim.x + threadIdx.x;
    if (t < N) mask[bat_items[t]] = 1;
}

__global__ void k_ratings(const float* __restrict__ hidden, const float* __restrict__ de_emb,
                          const float* __restrict__ de_bias,
                          const int* __restrict__ bat_idx, const int* __restrict__ bat_items,
                          float* __restrict__ out, int N) {
    const int l = threadIdx.x & 15;
    const int gid = (blockIdx.x * blockDim.x + threadIdx.x) >> 4;
    const int gstride = (gridDim.x * blockDim.x) >> 4;
    for (int n = gid; n < N; n += gstride) {
        int b  = bat_idx[n];
        int it = bat_items[n];
        float4 hv = *reinterpret_cast<const float4*>(hidden + (size_t)b  * 64 + l * 4);
        float4 dv = *reinterpret_cast<const float4*>(de_emb + (size_t)it * 64 + l * 4);
        float s = hv.x*dv.x + hv.y*dv.y + hv.z*dv.z + hv.w*dv.w;
        s += __shfl_xor(s, 1);
        s += __shfl_xor(s, 2);
        s += __shfl_xor(s, 4);
        s += __shfl_xor(s, 8);
        if (l == 0) out[n] = s + de_bias[it];
    }
}

__global__ void k_scatter(const int* __restrict__ sp_row, const int* __restrict__ sp_col,
                          const float* __restrict__ en_emb, float* __restrict__ hidden,
                          int nnz) {
    const int lane = threadIdx.x & 63;
    const int wave = (blockIdx.x * blockDim.x + threadIdx.x) >> 6;
    const int nwaves = (gridDim.x * blockDim.x) >> 6;
    for (int i = wave; i < nnz; i += nwaves) {
        if (!keep_mask(i, nnz)) continue;
        int row = sp_row[i];
        int col = sp_col[i];
        float v = 1.25f * en_emb[(size_t)col * 64 + lane];
        atomicAdd(&hidden[row * 64 + lane], v);
    }
}

__global__ void k_hfinish(float* __restrict__ hidden, const float* __restrict__ user_emb,
                          const int* __restrict__ user_ids, const float* __restrict__ en_off,
                          int B) {
    int t = blockIdx.x * blockDim.x + threadIdx.x;
    if (t >= B * 64) return;
    int b = t >> 6, d = t & 63;
    int uid = user_ids[b];
    float h = hidden[t] + user_emb[(size_t)uid * 64 + d] + en_off[d];
    hidden[t] = tanhf(h);
}

__global__ void k_reg_fb(const unsigned char* __restrict__ mask,
                         const float* __restrict__ en_emb, const float* __restrict__ de_emb,
                         const float* __restrict__ de_bias,
                         const float* __restrict__ user_emb, const int* __restrict__ user_ids,
                         const float* __restrict__ en_off,
                         float* __restrict__ reg, int num_items, int B) {
    const int stride = gridDim.x * blockDim.x;
    float s = 0.f;
    for (int t = blockIdx.x * blockDim.x + threadIdx.x; t < num_items * 16; t += stride) {
        int i = t >> 4, l = t & 15;
        if (mask[i]) {
            float4 e = *reinterpret_cast<const float4*>(en_emb + (size_t)i * 64 + l * 4);
            float4 d = *reinterpret_cast<const float4*>(de_emb + (size_t)i * 64 + l * 4);
            s += e.x*e.x + e.y*e.y + e.z*e.z + e.w*e.w
               + d.x*d.x + d.y*d.y + d.z*d.z + d.w*d.w;
            if (l == 0) { float bb = de_bias[i]; s += bb * bb; }
        }
    }
    for (int t = blockIdx.x * blockDim.x + threadIdx.x; t < B * 16; t += stride) {
        int b = t >> 4, l = t & 15;
        int uid = user_ids[b];
        float4 u = *reinterpret_cast<const float4*>(user_emb + (size_t)uid * 64 + l * 4);
        s += u.x*u.x + u.y*u.y + u.z*u.z + u.w*u.w;
    }
    if (blockIdx.x == 0 && threadIdx.x < 64) {
        float o = en_off[threadIdx.x];
        s += o * o;
    }
    for (int m = 1; m < 64; m <<= 1) s += __shfl_xor(s, m);
    __shared__ float wsum[4];
    if ((threadIdx.x & 63) == 0) wsum[threadIdx.x >> 6] = s;
    __syncthreads();
    if (threadIdx.x == 0)
        atomicAdd(reg, 0.5f * (wsum[0] + wsum[1] + wsum[2] + wsum[3]));
}

extern "C" void kernel_launch(void* const* d_in, const int* in_sizes, int n_in,
                              void* d_out, int out_size, void* d_ws, size_t ws_size,
                              hipStream_t stream) {
    const int*   user_ids  = (const int*)  d_in[0];
    const int*   bat_idx   = (const int*)  d_in[1];
    const int*   sp_row    = (const int*)  d_in[2];
    const int*   sp_col    = (const int*)  d_in[3];
    const int*   bat_items = (const int*)  d_in[4];
    const float* en_emb    = (const float*)d_in[5];
    const float* en_off    = (const float*)d_in[6];
    const float* de_emb    = (const float*)d_in[7];
    const float* de_bias   = (const float*)d_in[8];
    const float* user_emb  = (const float*)d_in[9];

    const int B         = in_sizes[0];
    const int N         = in_sizes[1];
    const int NNZ       = in_sizes[2];
    const int NUM_ITEMS = in_sizes[8];

    float* out = (float*)d_out;        // ratings [N]; reg scalar at out[N]

    // workspace: [mask | cursor | rowcur | reg_ws] one memset; rest no-init.
    char* ws = (char*)d_ws;
    size_t off = 0;
    unsigned char* mask = (unsigned char*)(ws + off);
    off += ((size_t)NUM_ITEMS + 255) & ~(size_t)255;
    int* cursor = (int*)(ws + off);               off += 256;
    int* rowcur = (int*)(ws + off);               off += (size_t)B * 4;
    float* reg_ws = (float*)(ws + off);           off += 256;
    const size_t zero_bytes = off;
    float* hidden = (float*)(ws + off);           off += (size_t)B * 64 * 4;  // fallback only
    off = (off + 15) & ~(size_t)15;
    uint2* perm2 = (uint2*)(ws + off);            off += (size_t)NB * CAPB * 8;
    unsigned* srow = (unsigned*)(ws + off);       off += (size_t)B * CAPR * 4;
    unsigned short* hb   = (unsigned short*)(ws + off);  off += (size_t)B * 64 * 2;
    off = (off + 15) & ~(size_t)15;
    unsigned short* debf = (unsigned short*)(ws + off);  off += (size_t)NUM_ITEMS * 64 * 2;
    float* sq = (float*)(ws + off);                      off += (size_t)NUM_ITEMS * 4;

    const bool sorted_path =
        (ws_size >= off) && (N == (1 << 20)) && (B == 4096) &&
        (NUM_ITEMS <= (1 << 17)) && (NUM_ITEMS >= 65536) &&
        (NUM_ITEMS % 4 == 0) &&
        (NNZ % (RSB * 256) == 0) && (NNZ / RSB <= CAPR * 256);

    hipMemsetAsync(ws, 0, zero_bytes, stream);

    if (sorted_path) {
        k_prep<<<256 + RSB + SCVT, 256, 0, stream>>>(
            bat_idx, bat_items, mask, cursor, perm2,
            sp_row, sp_col, rowcur, srow,
            en_emb, de_emb, de_bias, user_emb, user_ids, en_off,
            debf, sq, reg_ws, N, NUM_ITEMS, NNZ, B);
        k_hidden_reg<<<HBLK + REGF, 256, 0, stream>>>(
            srow, rowcur, en_emb, user_emb, user_ids, en_off, hb,
            mask, sq, reg_ws, B, NUM_ITEMS);
        k_ratings_bkt<<<FATB, 256, 0, stream>>>(hb, debf, de_bias, perm2, cursor,
                                                reg_ws, out, N);
    } else {
        hipMemsetAsync(hidden, 0, (size_t)B * 64 * 4, stream);
        hipMemsetAsync(out + N, 0, sizeof(float), stream);
        k_mask<<<(N + 255) / 256, 256, 0, stream>>>(bat_items, mask, N);
        k_scatter<<<FATB, 256, 0, stream>>>(sp_row, sp_col, en_emb, hidden, NNZ);
        k_hfinish<<<(B * 64 + 255) / 256, 256, 0, stream>>>(hidden, user_emb, user_ids,
                                                            en_off, B);
        k_ratings<<<FATB, 256, 0, stream>>>(hidden, de_emb, de_bias, bat_idx, bat_items, out, N);
        k_reg_fb<<<REGB_FB, 256, 0, stream>>>(mask, en_emb, de_emb, de_bias,
                                              user_emb, user_ids, en_off, out + N, NUM_ITEMS, B);
    }
}